// Round 12
// baseline (149.566 us; speedup 1.0000x reference)
//
#include <hip/hip_runtime.h>
#include <hip/hip_bf16.h>

// 1-NN VQ via split-bf16 MFMA + fused exact fp32 self-refinement.
//   score[q][k] = csq[k] - 2*dot(q,c_k); out = argmin_k (lowest-k tie-break).
// Phase 0 (knn_prep): codebook -> bf16 hi/lo fragment-ready cbB (part-major) + csq.
// Phase A (knn_mfma): 64 q/block, 4 waves = 2 mgroups x 2 ngroups.
//   Wave = 2 m-tiles x 8 n-tiles: acc[2][8] = 64 AGPR. A split-converted once
//   to regs (ah/al[2][4] = 64 VGPR). B staged hi->lo in 64 KB LDS.
//   dot ~= qh.ch + ql.ch + qh.cl (3-product, score err ~1.9e-3); per-wave
//   top-2 over 128 codes, ngroup merge in LDS; gap < T=0.004 -> IN-BLOCK
//   exact fp32 rescan of that query (codebook from L2, csq from LDS).
//   No worklist, no refine kernel, no 3rd launch.
// Ledger (rounds 2-11): M=32/wave tilings all plateau ~65us profiled
//   (LDS-pipe floor ~31us + barrier drains at 2 blk/CU, reg-capped
//   176/wave). A+acc>230 regs spills (r9/r10). Epilogue must stay fully
//   unrolled (r5); kb-with-global-loads must NOT be fully unrolled (r4).
//   r11 main loop kept byte-identical; self-refine appended after acc dies.

typedef __bf16 bf16x8 __attribute__((ext_vector_type(8)));
typedef float  floatx4 __attribute__((ext_vector_type(4)));

#define MFMA16 __builtin_amdgcn_mfma_f32_16x16x32_bf16

#define CSQ_OFF 1024
#define CBB_OFF 4096
#define T_FLAG  0.004f

__device__ __forceinline__ unsigned fmap(float f) {
    unsigned u = __float_as_uint(f);
    return (u & 0x80000000u) ? ~u : (u | 0x80000000u);
}
__device__ __forceinline__ float unfmap(unsigned u) {
    unsigned b = (u & 0x80000000u) ? (u ^ 0x80000000u) : ~u;
    return __uint_as_float(b);
}

// ---------------- Phase 0: codebook split, part-major fragment layout, csq ----------------
// cbB element index = part*32768 + ((t4*4 + kb)*64 + ln)*8 + j
//   part: 0=hi 1=lo; t4 = ntile 0..15; kb = k-chunk 0..3;
//   lane ln: n = t4*16 + (ln&15), k = kb*32 + (ln>>4)*8 + j.
__global__ void knn_prep(const float* __restrict__ cb, __bf16* __restrict__ cbB,
                         float* __restrict__ csq) {
    const int tid = threadIdx.x;
    const int id = blockIdx.x * 256 + tid;       // 0..8191
    const int part = id >> 12;
    const int rem = id & 4095;
    const int t4 = rem >> 8;
    const int kb = (rem >> 6) & 3;
    const int ln = id & 63;
    const int n = t4 * 16 + (ln & 15);
    const int k0 = kb * 32 + (ln >> 4) * 8;
    const float* src = cb + (size_t)n * 128 + k0;
    union { __bf16 h[8]; uint4 u; } p;
#pragma unroll
    for (int j = 0; j < 8; ++j) {
        float f = src[j];
        __bf16 hh = (__bf16)f;
        p.h[j] = (part == 0) ? hh : (__bf16)(f - (float)hh);
    }
    *(uint4*)(cbB + (size_t)id * 8) = p.u;

    if (blockIdx.x == 0) {
        const float4* row = (const float4*)(cb + (size_t)tid * 128);
        float a0 = 0.f, a1 = 0.f, a2 = 0.f, a3 = 0.f;
#pragma unroll 8
        for (int j = 0; j < 32; ++j) {
            float4 v = row[j];
            a0 = fmaf(v.x, v.x, a0);
            a1 = fmaf(v.y, v.y, a1);
            a2 = fmaf(v.z, v.z, a2);
            a3 = fmaf(v.w, v.w, a3);
        }
        csq[tid] = (a0 + a1) + (a2 + a3);
    }
}

// ---------------- Phase A: MFMA scores + top-2 + fused exact refine ----------------
__global__ __launch_bounds__(256, 2) void knn_mfma(const float* __restrict__ x,
                                                   const float* __restrict__ cb,
                                                   const __bf16* __restrict__ cbB,
                                                   const float* __restrict__ csq_g,
                                                   int* __restrict__ out) {
    __shared__ __bf16 sB[32768];                 // 64 KB: current B part
    __shared__ float s_csq[256];                 // 1 KB
    __shared__ unsigned long long sWb[128];      // 1 KB: [ql][ng] best
    __shared__ unsigned long long sWs[128];      // 1 KB: [ql][ng] second
    __shared__ unsigned long long s_red[4];
    __shared__ int s_nf;
    __shared__ int s_flagq[64];

    const int tid = threadIdx.x;
    const int wave = tid >> 6;
    const int lane = tid & 63;
    const int mg = wave >> 1;                    // m-group 0..1
    const int ng = wave & 1;                     // n-group 0..1
    const int rl = lane & 15;                    // m/n col within tile
    const int kg = lane >> 4;                    // k/row group 0..3

    s_csq[tid] = csq_g[tid];
    if (tid == 0) s_nf = 0;

    // ---- A: load + split-convert this wave's 2 m-tiles into registers ----
    const float* xq = x + ((size_t)blockIdx.x * 64 + mg * 32) * 128;
    bf16x8 ah[2][4], al[2][4];
#pragma unroll
    for (int m = 0; m < 2; ++m) {
#pragma unroll
        for (int kb = 0; kb < 4; ++kb) {
            const float* s = xq + (size_t)(m * 16 + rl) * 128 + kb * 32 + kg * 8;
            float4 f0 = *(const float4*)(s);
            float4 f1 = *(const float4*)(s + 4);
            float f[8] = {f0.x, f0.y, f0.z, f0.w, f1.x, f1.y, f1.z, f1.w};
            union { __bf16 h[8]; bf16x8 v; } ph, pl;
#pragma unroll
            for (int j = 0; j < 8; ++j) {
                __bf16 hh = (__bf16)f[j];
                ph.h[j] = hh;
                pl.h[j] = (__bf16)(f[j] - (float)hh);
            }
            ah[m][kb] = ph.v;
            al[m][kb] = pl.v;
        }
    }

    // ---- stage B hi (64 KB) ----
    {
        const uint4* src = (const uint4*)cbB;    // part 0
        uint4* dst = (uint4*)sB;
#pragma unroll 4
        for (int i = 0; i < 16; ++i) dst[i * 256 + tid] = src[i * 256 + tid];
    }
    __syncthreads();

    floatx4 acc[2][8];
#pragma unroll
    for (int m = 0; m < 2; ++m)
#pragma unroll
        for (int t = 0; t < 8; ++t) acc[m][t] = (floatx4){0.f, 0.f, 0.f, 0.f};

    // ---- hi phase: qh.ch + ql.ch ----
#pragma unroll
    for (int kb = 0; kb < 4; ++kb) {
#pragma unroll
        for (int t = 0; t < 8; ++t) {
            const int t4 = ng * 8 + t;
            bf16x8 b = *(const bf16x8*)(sB + (((t4 * 4 + kb) * 64 + lane) * 8));
            acc[0][t] = MFMA16(ah[0][kb], b, acc[0][t], 0, 0, 0);
            acc[1][t] = MFMA16(ah[1][kb], b, acc[1][t], 0, 0, 0);
            acc[0][t] = MFMA16(al[0][kb], b, acc[0][t], 0, 0, 0);
            acc[1][t] = MFMA16(al[1][kb], b, acc[1][t], 0, 0, 0);
        }
    }
    __syncthreads();   // hi reads done before overwrite

    // ---- stage B lo (64 KB) ----
    {
        const uint4* src = (const uint4*)(cbB + 32768);   // part 1
        uint4* dst = (uint4*)sB;
#pragma unroll 4
        for (int i = 0; i < 16; ++i) dst[i * 256 + tid] = src[i * 256 + tid];
    }
    __syncthreads();

    // ---- lo phase: qh.cl only (ql.cl dropped) ----
#pragma unroll
    for (int kb = 0; kb < 4; ++kb) {
#pragma unroll
        for (int t = 0; t < 8; ++t) {
            const int t4 = ng * 8 + t;
            bf16x8 b = *(const bf16x8*)(sB + (((t4 * 4 + kb) * 64 + lane) * 8));
            acc[0][t] = MFMA16(ah[0][kb], b, acc[0][t], 0, 0, 0);
            acc[1][t] = MFMA16(ah[1][kb], b, acc[1][t], 0, 0, 0);
        }
    }

    // ---- epilogue: per-wave top-2 over its 128 codes (FULLY unrolled) ----
    float cs[8];
#pragma unroll
    for (int t = 0; t < 8; ++t) cs[t] = s_csq[(ng * 8 + t) * 16 + rl];

#pragma unroll
    for (int m = 0; m < 2; ++m) {
#pragma unroll
        for (int r = 0; r < 4; ++r) {
            unsigned long long b = ~0ULL, s = ~0ULL;
#pragma unroll
            for (int t = 0; t < 8; ++t) {
                const int n = (ng * 8 + t) * 16 + rl;
                float score = fmaf(-2.0f, acc[m][t][r], cs[t]);
                unsigned long long key =
                    ((unsigned long long)fmap(score) << 32) | (unsigned)n;
                if (key < b) { s = b; b = key; }
                else if (key < s) { s = key; }
            }
#pragma unroll
            for (int d = 1; d < 16; d <<= 1) {
                unsigned long long ob = __shfl_xor(b, d);
                unsigned long long os = __shfl_xor(s, d);
                unsigned long long nb = ob < b ? ob : b;
                unsigned long long mx = ob < b ? b : ob;
                unsigned long long mn = os < s ? os : s;
                b = nb;
                s = mx < mn ? mx : mn;
            }
            if (rl == 0) {
                const int ql = mg * 32 + m * 16 + kg * 4 + r;   // 0..63
                sWb[ql * 2 + ng] = b;
                sWs[ql * 2 + ng] = s;
            }
        }
    }
    __syncthreads();

    // ---- merge the 2 n-groups, write out, flag near-ties locally ----
    if (tid < 64) {
        unsigned long long b0 = sWb[tid * 2 + 0], b1 = sWb[tid * 2 + 1];
        unsigned long long s0 = sWs[tid * 2 + 0], s1 = sWs[tid * 2 + 1];
        unsigned long long best = b0 < b1 ? b0 : b1;
        unsigned long long mx = b0 < b1 ? b1 : b0;
        unsigned long long mn = s0 < s1 ? s0 : s1;
        unsigned long long sec = mx < mn ? mx : mn;
        const size_t qg = (size_t)blockIdx.x * 64 + tid;
        out[qg] = (int)(unsigned)(best & 0xFFFFFFFFull);
        float f1 = unfmap((unsigned)(best >> 32));
        float f2 = unfmap((unsigned)(sec >> 32));
        if (f2 - f1 < T_FLAG) {
            int i = atomicAdd(&s_nf, 1);
            s_flagq[i] = tid;
        }
    }
    __syncthreads();

    // ---- fused exact fp32 rescan of flagged queries (rare: ~0.2%) ----
    const int nf = s_nf;
    for (int i = 0; i < nf; ++i) {
        const int lq = s_flagq[i];
        const size_t q = (size_t)blockIdx.x * 64 + lq;
        const float4* qr = (const float4*)(x + q * 128);
        const float4* cr = (const float4*)(cb + (size_t)tid * 128);
        float a0 = 0.f, a1 = 0.f, a2 = 0.f, a3 = 0.f;
#pragma unroll 8
        for (int c4 = 0; c4 < 32; ++c4) {
            float4 qv = qr[c4];            // broadcast (same addr all lanes)
            float4 cv = cr[c4];
            a0 = fmaf(qv.x, cv.x, a0);
            a1 = fmaf(qv.y, cv.y, a1);
            a2 = fmaf(qv.z, cv.z, a2);
            a3 = fmaf(qv.w, cv.w, a3);
        }
        float dot = (a0 + a1) + (a2 + a3);
        float score = fmaf(-2.0f, dot, s_csq[tid]);
        unsigned long long key =
            ((unsigned long long)fmap(score) << 32) | (unsigned)tid;
#pragma unroll
        for (int d = 1; d < 64; d <<= 1) {
            unsigned long long o = __shfl_xor(key, d);
            key = o < key ? o : key;
        }
        if (lane == 0) s_red[wave] = key;
        __syncthreads();
        if (tid == 0) {
            unsigned long long b = s_red[0];
            unsigned long long o;
            o = s_red[1]; b = o < b ? o : b;
            o = s_red[2]; b = o < b ? o : b;
            o = s_red[3]; b = o < b ? o : b;
            out[q] = (int)(unsigned)(b & 0xFFFFFFFFull);
        }
        __syncthreads();
    }
}

extern "C" void kernel_launch(void* const* d_in, const int* in_sizes, int n_in,
                              void* d_out, int out_size, void* d_ws, size_t ws_size,
                              hipStream_t stream) {
    const float* x = (const float*)d_in[0];
    const float* cb = (const float*)d_in[1];
    int* out = (int*)d_out;

    char* ws = (char*)d_ws;
    float* csq = (float*)(ws + CSQ_OFF);
    __bf16* cbB = (__bf16*)(ws + CBB_OFF);

    const int M = in_sizes[0] / 128;     // 131072

    knn_prep<<<32, 256, 0, stream>>>(cb, cbB, csq);
    knn_mfma<<<M / 64, 256, 0, stream>>>(x, cb, cbB, csq, out);
}

// Round 13
// 147.375 us; speedup vs baseline: 1.0149x; 1.0149x over previous
//
#include <hip/hip_runtime.h>
#include <hip/hip_bf16.h>

// 1-NN VQ via split-bf16 MFMA + fused exact fp32 self-refinement.
//   score[q][k] = csq[k] - 2*dot(q,c_k); out = argmin_k (lowest-k tie-break).
// Phase 0 (knn_prep): codebook -> bf16 hi/lo fragment-ready cbB (part-major) + csq.
// Phase A (knn_mfma): 128 q/block, 4 waves; wave = 2 m-tiles (32 q) x 8 n-tiles.
//   All waves share the n-set; n is chunked: nc=0 -> codes 0..127, nc=1 ->
//   128..255. Per nc: stage B-hi chunk (32 KB) via global_load_lds(16B),
//   MFMA hi (qh.ch + ql.ch), stage B-lo chunk, MFMA lo (qh.cl), partial
//   top-2 epilogue; running top-2 carried across chunks in 2 KB LDS.
//   A split-converted once to regs (ah/al[2][4] = 64 VGPR).
//   gap < T=0.004 -> in-block exact fp32 rescan (codebook from L2).
// r13 vs r12: plateau diagnosis = latency/barrier-bound at 2 blk/CU (no pipe
//   near 65us: LDS ~15us, MFMA ~3us, VALU 30%). Levers: (1) 32 KB staging
//   chunks -> LDS 69->36 KB -> launch_bounds(256,3) -> 3 blk/CU; (2) DMA
//   staging via global_load_lds (no VGPR round-trip; layout is wave-uniform
//   base + lane*16, satisfying the scatter constraint).
// Ledger: epilogue/acc must stay const-indexed+fully unrolled (r5 scratch);
//   unrolled global-load loops spill (r4); A+acc > ~230 unified regs spills
//   (r9/r10). Watch WRITE_SIZE: >5 MB here = (256,3) forced a spill.

typedef __bf16 bf16x8 __attribute__((ext_vector_type(8)));
typedef float  floatx4 __attribute__((ext_vector_type(4)));

#define MFMA16 __builtin_amdgcn_mfma_f32_16x16x32_bf16

#define CSQ_OFF 1024
#define CBB_OFF 4096
#define T_FLAG  0.004f

typedef const __attribute__((address_space(1))) unsigned int* as1_u32p;
typedef __attribute__((address_space(3))) unsigned int* as3_u32p;

__device__ __forceinline__ void cp16_g2l(const void* g, void* l) {
    __builtin_amdgcn_global_load_lds((as1_u32p)g, (as3_u32p)l, 16, 0, 0);
}

__device__ __forceinline__ unsigned fmap(float f) {
    unsigned u = __float_as_uint(f);
    return (u & 0x80000000u) ? ~u : (u | 0x80000000u);
}
__device__ __forceinline__ float unfmap(unsigned u) {
    unsigned b = (u & 0x80000000u) ? (u ^ 0x80000000u) : ~u;
    return __uint_as_float(b);
}

// ---------------- Phase 0: codebook split, part-major fragment layout, csq ----------------
// cbB element index = part*32768 + ((t4*4 + kb)*64 + ln)*8 + j
//   part: 0=hi 1=lo; t4 = ntile 0..15; kb = k-chunk 0..3;
//   lane ln: n = t4*16 + (ln&15), k = kb*32 + (ln>>4)*8 + j.
// nc chunk (8 n-tiles) = contiguous 16384 elements (32 KB) within a part.
__global__ void knn_prep(const float* __restrict__ cb, __bf16* __restrict__ cbB,
                         float* __restrict__ csq) {
    const int tid = threadIdx.x;
    const int id = blockIdx.x * 256 + tid;       // 0..8191
    const int part = id >> 12;
    const int rem = id & 4095;
    const int t4 = rem >> 8;
    const int kb = (rem >> 6) & 3;
    const int ln = id & 63;
    const int n = t4 * 16 + (ln & 15);
    const int k0 = kb * 32 + (ln >> 4) * 8;
    const float* src = cb + (size_t)n * 128 + k0;
    union { __bf16 h[8]; uint4 u; } p;
#pragma unroll
    for (int j = 0; j < 8; ++j) {
        float f = src[j];
        __bf16 hh = (__bf16)f;
        p.h[j] = (part == 0) ? hh : (__bf16)(f - (float)hh);
    }
    *(uint4*)(cbB + (size_t)id * 8) = p.u;

    if (blockIdx.x == 0) {
        const float4* row = (const float4*)(cb + (size_t)tid * 128);
        float a0 = 0.f, a1 = 0.f, a2 = 0.f, a3 = 0.f;
#pragma unroll 8
        for (int j = 0; j < 32; ++j) {
            float4 v = row[j];
            a0 = fmaf(v.x, v.x, a0);
            a1 = fmaf(v.y, v.y, a1);
            a2 = fmaf(v.z, v.z, a2);
            a3 = fmaf(v.w, v.w, a3);
        }
        csq[tid] = (a0 + a1) + (a2 + a3);
    }
}

// ---------------- Phase A: MFMA scores + chunked top-2 + fused exact refine ----------------
__global__ __launch_bounds__(256, 3) void knn_mfma(const float* __restrict__ x,
                                                   const float* __restrict__ cb,
                                                   const __bf16* __restrict__ cbB,
                                                   const float* __restrict__ csq_g,
                                                   int* __restrict__ out) {
    __shared__ __bf16 sB[16384];                 // 32 KB: current B chunk
    __shared__ float s_csq[256];                 // 1 KB
    __shared__ unsigned long long sT2[4][32][2]; // 2 KB: per-wave per-query top2
    __shared__ unsigned long long s_red[4];
    __shared__ int s_nf;
    __shared__ int s_flagq[128];

    const int tid = threadIdx.x;
    const int wave = tid >> 6;
    const int lane = tid & 63;
    const int rl = lane & 15;                    // m/n col within tile
    const int kg = lane >> 4;                    // k/row group 0..3

    s_csq[tid] = csq_g[tid];
    if (tid == 0) s_nf = 0;

    // ---- A: load + split-convert this wave's 2 m-tiles (32 q) into registers ----
    const float* xq = x + ((size_t)blockIdx.x * 128 + wave * 32) * 128;
    bf16x8 ah[2][4], al[2][4];
#pragma unroll
    for (int m = 0; m < 2; ++m) {
#pragma unroll
        for (int kb = 0; kb < 4; ++kb) {
            const float* s = xq + (size_t)(m * 16 + rl) * 128 + kb * 32 + kg * 8;
            float4 f0 = *(const float4*)(s);
            float4 f1 = *(const float4*)(s + 4);
            float f[8] = {f0.x, f0.y, f0.z, f0.w, f1.x, f1.y, f1.z, f1.w};
            union { __bf16 h[8]; bf16x8 v; } ph, pl;
#pragma unroll
            for (int j = 0; j < 8; ++j) {
                __bf16 hh = (__bf16)f[j];
                ph.h[j] = hh;
                pl.h[j] = (__bf16)(f[j] - (float)hh);
            }
            ah[m][kb] = ph.v;
            al[m][kb] = pl.v;
        }
    }
    __syncthreads();   // s_csq/s_nf visible; sB untouched yet

    floatx4 acc[2][8];
#pragma unroll
    for (int m = 0; m < 2; ++m)
#pragma unroll
        for (int t = 0; t < 8; ++t) acc[m][t] = (floatx4){0.f, 0.f, 0.f, 0.f};

#pragma unroll 1
    for (int nc = 0; nc < 2; ++nc) {
        // ---- stage B hi chunk (32 KB) via async DMA ----
        {
            const __bf16* src = cbB + nc * 16384 + (size_t)tid * 8;
            __bf16* dst = sB + tid * 8;
#pragma unroll
            for (int i = 0; i < 8; ++i)
                cp16_g2l(src + i * 2048, dst + i * 2048);
        }
        __syncthreads();

        // ---- MFMA hi: qh.ch + ql.ch ----
#pragma unroll
        for (int kb = 0; kb < 4; ++kb) {
#pragma unroll
            for (int t = 0; t < 8; ++t) {
                bf16x8 b = *(const bf16x8*)(sB + (((t * 4 + kb) * 64 + lane) * 8));
                acc[0][t] = MFMA16(ah[0][kb], b, acc[0][t], 0, 0, 0);
                acc[1][t] = MFMA16(ah[1][kb], b, acc[1][t], 0, 0, 0);
                acc[0][t] = MFMA16(al[0][kb], b, acc[0][t], 0, 0, 0);
                acc[1][t] = MFMA16(al[1][kb], b, acc[1][t], 0, 0, 0);
            }
        }
        __syncthreads();   // hi reads done before overwrite

        // ---- stage B lo chunk (32 KB) ----
        {
            const __bf16* src = cbB + 32768 + nc * 16384 + (size_t)tid * 8;
            __bf16* dst = sB + tid * 8;
#pragma unroll
            for (int i = 0; i < 8; ++i)
                cp16_g2l(src + i * 2048, dst + i * 2048);
        }
        __syncthreads();

        // ---- MFMA lo: qh.cl only (ql.cl dropped) ----
#pragma unroll
        for (int kb = 0; kb < 4; ++kb) {
#pragma unroll
            for (int t = 0; t < 8; ++t) {
                bf16x8 b = *(const bf16x8*)(sB + (((t * 4 + kb) * 64 + lane) * 8));
                acc[0][t] = MFMA16(ah[0][kb], b, acc[0][t], 0, 0, 0);
                acc[1][t] = MFMA16(ah[1][kb], b, acc[1][t], 0, 0, 0);
            }
        }

        // ---- partial epilogue for this chunk's 128 codes (FULLY unrolled) ----
        float cs[8];
#pragma unroll
        for (int t = 0; t < 8; ++t) cs[t] = s_csq[(nc * 8 + t) * 16 + rl];

#pragma unroll
        for (int m = 0; m < 2; ++m) {
#pragma unroll
            for (int r = 0; r < 4; ++r) {
                unsigned long long b = ~0ULL, s = ~0ULL;
#pragma unroll
                for (int t = 0; t < 8; ++t) {
                    const int n = (nc * 8 + t) * 16 + rl;
                    float score = fmaf(-2.0f, acc[m][t][r], cs[t]);
                    unsigned long long key =
                        ((unsigned long long)fmap(score) << 32) | (unsigned)n;
                    if (key < b) { s = b; b = key; }
                    else if (key < s) { s = key; }
                }
#pragma unroll
                for (int d = 1; d < 16; d <<= 1) {
                    unsigned long long ob = __shfl_xor(b, d);
                    unsigned long long os = __shfl_xor(s, d);
                    unsigned long long nb = ob < b ? ob : b;
                    unsigned long long mx = ob < b ? b : ob;
                    unsigned long long mn = os < s ? os : s;
                    b = nb;
                    s = mx < mn ? mx : mn;
                }
                if (rl == 0) {
                    const int ql = m * 16 + kg * 4 + r;   // 0..31 within wave
                    if (nc == 0) {
                        sT2[wave][ql][0] = b;
                        sT2[wave][ql][1] = s;
                    } else {
                        unsigned long long b0 = sT2[wave][ql][0];
                        unsigned long long s0 = sT2[wave][ql][1];
                        unsigned long long best = b0 < b ? b0 : b;
                        unsigned long long mx = b0 < b ? b : b0;
                        unsigned long long mn = s0 < s ? s0 : s;
                        unsigned long long sec = mx < mn ? mx : mn;
                        const size_t qg = (size_t)blockIdx.x * 128
                                          + wave * 32 + ql;
                        out[qg] = (int)(unsigned)(best & 0xFFFFFFFFull);
                        float f1 = unfmap((unsigned)(best >> 32));
                        float f2 = unfmap((unsigned)(sec >> 32));
                        if (f2 - f1 < T_FLAG) {
                            int i = atomicAdd(&s_nf, 1);
                            s_flagq[i] = wave * 32 + ql;
                        }
                    }
                }
            }
        }

        // reset acc for the next chunk (const-indexed)
        if (nc == 0) {
#pragma unroll
            for (int m = 0; m < 2; ++m)
#pragma unroll
                for (int t = 0; t < 8; ++t)
                    acc[m][t] = (floatx4){0.f, 0.f, 0.f, 0.f};
        }
        __syncthreads();   // sB reads done before next stage / refine ordering
    }

    // ---- fused exact fp32 rescan of flagged queries (rare: ~0.2%) ----
    const int nf = s_nf;
    for (int i = 0; i < nf; ++i) {
        const int lq = s_flagq[i];
        const size_t q = (size_t)blockIdx.x * 128 + lq;
        const float4* qr = (const float4*)(x + q * 128);
        const float4* cr = (const float4*)(cb + (size_t)tid * 128);
        float a0 = 0.f, a1 = 0.f, a2 = 0.f, a3 = 0.f;
#pragma unroll 8
        for (int c4 = 0; c4 < 32; ++c4) {
            float4 qv = qr[c4];            // broadcast (same addr all lanes)
            float4 cv = cr[c4];
            a0 = fmaf(qv.x, cv.x, a0);
            a1 = fmaf(qv.y, cv.y, a1);
            a2 = fmaf(qv.z, cv.z, a2);
            a3 = fmaf(qv.w, cv.w, a3);
        }
        float dot = (a0 + a1) + (a2 + a3);
        float score = fmaf(-2.0f, dot, s_csq[tid]);
        unsigned long long key =
            ((unsigned long long)fmap(score) << 32) | (unsigned)tid;
#pragma unroll
        for (int d = 1; d < 64; d <<= 1) {
            unsigned long long o = __shfl_xor(key, d);
            key = o < key ? o : key;
        }
        if (lane == 0) s_red[wave] = key;
        __syncthreads();
        if (tid == 0) {
            unsigned long long b = s_red[0];
            unsigned long long o;
            o = s_red[1]; b = o < b ? o : b;
            o = s_red[2]; b = o < b ? o : b;
            o = s_red[3]; b = o < b ? o : b;
            out[q] = (int)(unsigned)(b & 0xFFFFFFFFull);
        }
        __syncthreads();
    }
}

extern "C" void kernel_launch(void* const* d_in, const int* in_sizes, int n_in,
                              void* d_out, int out_size, void* d_ws, size_t ws_size,
                              hipStream_t stream) {
    const float* x = (const float*)d_in[0];
    const float* cb = (const float*)d_in[1];
    int* out = (int*)d_out;

    char* ws = (char*)d_ws;
    float* csq = (float*)(ws + CSQ_OFF);
    __bf16* cbB = (__bf16*)(ws + CBB_OFF);

    const int M = in_sizes[0] / 128;     // 131072

    knn_prep<<<32, 256, 0, stream>>>(cb, cbB, csq);
    knn_mfma<<<M / 128, 256, 0, stream>>>(x, cb, cbB, csq, out);
}

// Round 14
// 146.651 us; speedup vs baseline: 1.0199x; 1.0049x over previous
//
#include <hip/hip_runtime.h>
#include <hip/hip_bf16.h>

// 1-NN VQ via split-bf16 MFMA + exact fp32 refinement.
//   score[q][k] = csq[k] - 2*dot(q,c_k); out = argmin_k (lowest-k tie-break).
// Phase 0 (knn_prep): codebook -> bf16 hi/lo fragment-ready cbB (part-major) + csq.
// Phase A (knn_mfma): 64 q/block, 4 waves = 2 mgroups x 2 ngroups.
//   Wave = 2 m-tiles x 8 n-tiles: acc[2][8] = 64 AGPR. A split-converted once
//   to regs (ah/al[2][4] = 64 VGPR). HI part staged once in 64 KB LDS
//   (2 MFMAs per ds_read); LO part streamed per-wave from L2 (1 read : 2 MFMA,
//   +0.26 GB L2 ~ 8 us) -- removes the 2nd staging pass and 2 barrier drains
//   and 1/3 of LDS-pipe traffic vs r11. dot ~= qh.ch + ql.ch + qh.cl
//   (3-product, score err ~1.9e-3); per-wave top-2, ngroup merge in LDS;
//   gap < T=0.004 -> worklist. Phase B (knn_refine): exact fp32 rescan.
// Ledger: r6 62us (all-L2: 1GB L2 wall) | r11 66us (all-LDS: LDS+barrier wall)
//   | breakout attempts r7/r9/r10/r13 = 75/97/423/90 (occupancy/spill traps).
//   This hybrid splits the B-traffic between the two walls. Constraints:
//   acc/A const-indexed + fully unrolled (r5); lo's 32 unrolled global loads
//   fenced mid-way with sched_barrier(0) to cap live B regs (r4/r10 spill
//   mechanism); budget ~217/256 at 2 waves/SIMD. WRITE_SIZE > 5 MB = spill.

typedef __bf16 bf16x8 __attribute__((ext_vector_type(8)));
typedef float  floatx4 __attribute__((ext_vector_type(4)));

#define MFMA16 __builtin_amdgcn_mfma_f32_16x16x32_bf16

#define CNT_OFF 0
#define CSQ_OFF 1024
#define CBB_OFF 4096
#define WL_OFF  (4096 + 131072)
#define WL_CAP  32768
#define T_FLAG  0.004f

__device__ __forceinline__ unsigned fmap(float f) {
    unsigned u = __float_as_uint(f);
    return (u & 0x80000000u) ? ~u : (u | 0x80000000u);
}
__device__ __forceinline__ float unfmap(unsigned u) {
    unsigned b = (u & 0x80000000u) ? (u ^ 0x80000000u) : ~u;
    return __uint_as_float(b);
}

// ---------------- Phase 0: codebook split, part-major fragment layout, csq ----------------
// cbB element index = part*32768 + ((t4*4 + kb)*64 + ln)*8 + j
//   part: 0=hi 1=lo; t4 = ntile 0..15; kb = k-chunk 0..3;
//   lane ln: n = t4*16 + (ln&15), k = kb*32 + (ln>>4)*8 + j.
__global__ void knn_prep(const float* __restrict__ cb, __bf16* __restrict__ cbB,
                         float* __restrict__ csq, int* __restrict__ cnt) {
    const int tid = threadIdx.x;
    const int id = blockIdx.x * 256 + tid;       // 0..8191
    if (id == 0) *cnt = 0;
    const int part = id >> 12;
    const int rem = id & 4095;
    const int t4 = rem >> 8;
    const int kb = (rem >> 6) & 3;
    const int ln = id & 63;
    const int n = t4 * 16 + (ln & 15);
    const int k0 = kb * 32 + (ln >> 4) * 8;
    const float* src = cb + (size_t)n * 128 + k0;
    union { __bf16 h[8]; uint4 u; } p;
#pragma unroll
    for (int j = 0; j < 8; ++j) {
        float f = src[j];
        __bf16 hh = (__bf16)f;
        p.h[j] = (part == 0) ? hh : (__bf16)(f - (float)hh);
    }
    *(uint4*)(cbB + (size_t)id * 8) = p.u;

    if (blockIdx.x == 0) {
        const float4* row = (const float4*)(cb + (size_t)tid * 128);
        float a0 = 0.f, a1 = 0.f, a2 = 0.f, a3 = 0.f;
#pragma unroll 8
        for (int j = 0; j < 32; ++j) {
            float4 v = row[j];
            a0 = fmaf(v.x, v.x, a0);
            a1 = fmaf(v.y, v.y, a1);
            a2 = fmaf(v.z, v.z, a2);
            a3 = fmaf(v.w, v.w, a3);
        }
        csq[tid] = (a0 + a1) + (a2 + a3);
    }
}

// ---------------- Phase A: MFMA scores + top-2 + flag ----------------
__global__ __launch_bounds__(256, 2) void knn_mfma(const float* __restrict__ x,
                                                   const __bf16* __restrict__ cbB,
                                                   const float* __restrict__ csq_g,
                                                   int* __restrict__ out,
                                                   int* __restrict__ cnt,
                                                   int* __restrict__ wl) {
    __shared__ __bf16 sB[32768];                 // 64 KB: B hi part (resident)
    __shared__ float s_csq[256];                 // 1 KB
    __shared__ unsigned long long sWb[128];      // 1 KB: [ql][ng] best
    __shared__ unsigned long long sWs[128];      // 1 KB: [ql][ng] second

    const int tid = threadIdx.x;
    const int wave = tid >> 6;
    const int lane = tid & 63;
    const int mg = wave >> 1;                    // m-group 0..1
    const int ng = wave & 1;                     // n-group 0..1
    const int rl = lane & 15;                    // m/n col within tile
    const int kg = lane >> 4;                    // k/row group 0..3

    s_csq[tid] = csq_g[tid];

    // ---- A: load + split-convert this wave's 2 m-tiles into registers ----
    const float* xq = x + ((size_t)blockIdx.x * 64 + mg * 32) * 128;
    bf16x8 ah[2][4], al[2][4];
#pragma unroll
    for (int m = 0; m < 2; ++m) {
#pragma unroll
        for (int kb = 0; kb < 4; ++kb) {
            const float* s = xq + (size_t)(m * 16 + rl) * 128 + kb * 32 + kg * 8;
            float4 f0 = *(const float4*)(s);
            float4 f1 = *(const float4*)(s + 4);
            float f[8] = {f0.x, f0.y, f0.z, f0.w, f1.x, f1.y, f1.z, f1.w};
            union { __bf16 h[8]; bf16x8 v; } ph, pl;
#pragma unroll
            for (int j = 0; j < 8; ++j) {
                __bf16 hh = (__bf16)f[j];
                ph.h[j] = hh;
                pl.h[j] = (__bf16)(f[j] - (float)hh);
            }
            ah[m][kb] = ph.v;
            al[m][kb] = pl.v;
        }
    }

    // ---- stage B hi (64 KB) once ----
    {
        const uint4* src = (const uint4*)cbB;    // part 0
        uint4* dst = (uint4*)sB;
#pragma unroll 4
        for (int i = 0; i < 16; ++i) dst[i * 256 + tid] = src[i * 256 + tid];
    }
    __syncthreads();

    floatx4 acc[2][8];
#pragma unroll
    for (int m = 0; m < 2; ++m)
#pragma unroll
        for (int t = 0; t < 8; ++t) acc[m][t] = (floatx4){0.f, 0.f, 0.f, 0.f};

    // ---- hi phase (LDS): qh.ch + ql.ch ----
#pragma unroll
    for (int kb = 0; kb < 4; ++kb) {
#pragma unroll
        for (int t = 0; t < 8; ++t) {
            const int t4 = ng * 8 + t;
            bf16x8 b = *(const bf16x8*)(sB + (((t4 * 4 + kb) * 64 + lane) * 8));
            acc[0][t] = MFMA16(ah[0][kb], b, acc[0][t], 0, 0, 0);
            acc[1][t] = MFMA16(ah[1][kb], b, acc[1][t], 0, 0, 0);
            acc[0][t] = MFMA16(al[0][kb], b, acc[0][t], 0, 0, 0);
            acc[1][t] = MFMA16(al[1][kb], b, acc[1][t], 0, 0, 0);
        }
    }

    // ---- lo phase (L2 stream): qh.cl only (ql.cl dropped) ----
    // Fully unrolled (A const-indexed); fence between halves caps live B regs.
    const __bf16* cbLo = cbB + 32768;
#pragma unroll
    for (int kb = 0; kb < 2; ++kb) {
#pragma unroll
        for (int t = 0; t < 8; ++t) {
            const int t4 = ng * 8 + t;
            bf16x8 b = *(const bf16x8*)(cbLo + (((t4 * 4 + kb) * 64 + lane) * 8));
            acc[0][t] = MFMA16(ah[0][kb], b, acc[0][t], 0, 0, 0);
            acc[1][t] = MFMA16(ah[1][kb], b, acc[1][t], 0, 0, 0);
        }
    }
    __builtin_amdgcn_sched_barrier(0);   // cap hoisted-load live range
#pragma unroll
    for (int kb = 2; kb < 4; ++kb) {
#pragma unroll
        for (int t = 0; t < 8; ++t) {
            const int t4 = ng * 8 + t;
            bf16x8 b = *(const bf16x8*)(cbLo + (((t4 * 4 + kb) * 64 + lane) * 8));
            acc[0][t] = MFMA16(ah[0][kb], b, acc[0][t], 0, 0, 0);
            acc[1][t] = MFMA16(ah[1][kb], b, acc[1][t], 0, 0, 0);
        }
    }

    // ---- epilogue: per-wave top-2 over its 128 codes (FULLY unrolled) ----
    float cs[8];
#pragma unroll
    for (int t = 0; t < 8; ++t) cs[t] = s_csq[(ng * 8 + t) * 16 + rl];

#pragma unroll
    for (int m = 0; m < 2; ++m) {
#pragma unroll
        for (int r = 0; r < 4; ++r) {
            unsigned long long b = ~0ULL, s = ~0ULL;
#pragma unroll
            for (int t = 0; t < 8; ++t) {
                const int n = (ng * 8 + t) * 16 + rl;
                float score = fmaf(-2.0f, acc[m][t][r], cs[t]);
                unsigned long long key =
                    ((unsigned long long)fmap(score) << 32) | (unsigned)n;
                if (key < b) { s = b; b = key; }
                else if (key < s) { s = key; }
            }
#pragma unroll
            for (int d = 1; d < 16; d <<= 1) {
                unsigned long long ob = __shfl_xor(b, d);
                unsigned long long os = __shfl_xor(s, d);
                unsigned long long nb = ob < b ? ob : b;
                unsigned long long mx = ob < b ? b : ob;
                unsigned long long mn = os < s ? os : s;
                b = nb;
                s = mx < mn ? mx : mn;
            }
            if (rl == 0) {
                const int ql = mg * 32 + m * 16 + kg * 4 + r;   // 0..63
                sWb[ql * 2 + ng] = b;
                sWs[ql * 2 + ng] = s;
            }
        }
    }
    __syncthreads();

    // ---- merge the 2 n-groups, write out, flag near-ties ----
    if (tid < 64) {
        unsigned long long b0 = sWb[tid * 2 + 0], b1 = sWb[tid * 2 + 1];
        unsigned long long s0 = sWs[tid * 2 + 0], s1 = sWs[tid * 2 + 1];
        unsigned long long best = b0 < b1 ? b0 : b1;
        unsigned long long mx = b0 < b1 ? b1 : b0;
        unsigned long long mn = s0 < s1 ? s0 : s1;
        unsigned long long sec = mx < mn ? mx : mn;
        const size_t qg = (size_t)blockIdx.x * 64 + tid;
        out[qg] = (int)(unsigned)(best & 0xFFFFFFFFull);
        float f1 = unfmap((unsigned)(best >> 32));
        float f2 = unfmap((unsigned)(sec >> 32));
        if (f2 - f1 < T_FLAG) {
            int idx = atomicAdd(cnt, 1);
            if (idx < WL_CAP) wl[idx] = (int)qg;
        }
    }
}

// ---------------- Phase B: exact fp32 rescan, block-per-query ----------------
__global__ __launch_bounds__(256) void knn_refine(const float* __restrict__ x,
                                                  const float* __restrict__ cb,
                                                  const float* __restrict__ csq_g,
                                                  const int* __restrict__ wl,
                                                  const int* __restrict__ cnt,
                                                  int* __restrict__ out) {
    __shared__ unsigned long long sP[4];
    const int tid = threadIdx.x;           // == code index k
    const int lane = tid & 63;
    const int wave = tid >> 6;

    int n = *cnt;
    if (n > WL_CAP) n = WL_CAP;
    const float mycsq = csq_g[tid];
    const float4* cr = (const float4*)(cb + (size_t)tid * 128);

    for (int i = blockIdx.x; i < n; i += gridDim.x) {
        const int q = wl[i];
        const float4* qr = (const float4*)(x + (size_t)q * 128);
        float a0 = 0.f, a1 = 0.f, a2 = 0.f, a3 = 0.f;
#pragma unroll 8
        for (int c4 = 0; c4 < 32; ++c4) {
            float4 qv = qr[c4];            // broadcast (same addr all lanes)
            float4 cv = cr[c4];
            a0 = fmaf(qv.x, cv.x, a0);
            a1 = fmaf(qv.y, cv.y, a1);
            a2 = fmaf(qv.z, cv.z, a2);
            a3 = fmaf(qv.w, cv.w, a3);
        }
        float dot = (a0 + a1) + (a2 + a3);
        float score = fmaf(-2.0f, dot, mycsq);
        unsigned long long key =
            ((unsigned long long)fmap(score) << 32) | (unsigned)tid;
#pragma unroll
        for (int d = 1; d < 64; d <<= 1) {
            unsigned long long o = __shfl_xor(key, d);
            key = o < key ? o : key;
        }
        if (lane == 0) sP[wave] = key;
        __syncthreads();
        if (tid == 0) {
            unsigned long long b = sP[0];
            unsigned long long o;
            o = sP[1]; b = o < b ? o : b;
            o = sP[2]; b = o < b ? o : b;
            o = sP[3]; b = o < b ? o : b;
            out[q] = (int)(unsigned)(b & 0xFFFFFFFFull);
        }
        __syncthreads();
    }
}

extern "C" void kernel_launch(void* const* d_in, const int* in_sizes, int n_in,
                              void* d_out, int out_size, void* d_ws, size_t ws_size,
                              hipStream_t stream) {
    const float* x = (const float*)d_in[0];
    const float* cb = (const float*)d_in[1];
    int* out = (int*)d_out;

    char* ws = (char*)d_ws;
    int* cnt = (int*)(ws + CNT_OFF);
    float* csq = (float*)(ws + CSQ_OFF);
    __bf16* cbB = (__bf16*)(ws + CBB_OFF);
    int* wl = (int*)(ws + WL_OFF);

    const int M = in_sizes[0] / 128;     // 131072

    knn_prep<<<32, 256, 0, stream>>>(cb, cbB, csq, cnt);
    knn_mfma<<<M / 64, 256, 0, stream>>>(x, cbB, csq, out, cnt, wl);
    knn_refine<<<240, 256, 0, stream>>>(x, cb, csq, wl, cnt, out);
}